// Round 6
// baseline (1570.926 us; speedup 1.0000x reference)
//
#include <hip/hip_runtime.h>

typedef short s16x8 __attribute__((ext_vector_type(8)));
typedef float f32x4 __attribute__((ext_vector_type(4)));

static constexpr int NN = 50000;
static constexpr int NE = 1600000;

__device__ __forceinline__ unsigned short f2b(float f) {
  union { float f; unsigned u; } c; c.f = f;
  unsigned x = c.u;
  x += 0x7fffu + ((x >> 16) & 1u);
  return (unsigned short)(x >> 16);
}
__device__ __forceinline__ int clampi(int v, int lo, int hi) {
  return v < lo ? lo : (v > hi ? hi : v);
}
__device__ __forceinline__ int rdl_i(int v, int l) {
  return __builtin_amdgcn_readlane(v, l);
}
__device__ __forceinline__ float rdl_f(float v, int l) {
  union { float f; int i; } c; c.f = v;
  c.i = __builtin_amdgcn_readlane(c.i, l);
  return c.f;
}
// global -> LDS direct copy, 16B per lane. LDS dest is wave-uniform base;
// HW writes base + lane*16. Global src is per-lane.
__device__ __forceinline__ void gl_lds16(const void* g, void* l) {
  __builtin_amdgcn_global_load_lds((const __attribute__((address_space(1))) void*)g,
                                   (__attribute__((address_space(3))) void*)l, 16, 0, 0);
}

// ---------------- f32 -> bf16 weight conversion ----------------
__global__ __launch_bounds__(256) void k_cvt(const float* __restrict__ s,
                                             unsigned short* __restrict__ d, int n) {
  const int i = blockIdx.x * 256 + threadIdx.x;
  if (i < n) d[i] = f2b(s[i]);
}

// ---------------- CSR build ----------------
__global__ __launch_bounds__(256) void k_count(const int* __restrict__ dst,
                                               int* __restrict__ counts, int E) {
  const int e = blockIdx.x * 256 + threadIdx.x;
  if (e < E) atomicAdd(&counts[clampi(dst[e], 0, NN - 1)], 1);
}

// wave-scan reserve: one atomic per wave instead of 50000 same-address atomics.
__global__ __launch_bounds__(256) void k_reserve(const int* __restrict__ counts,
                                                 int* __restrict__ offs,
                                                 int* __restrict__ cursor,
                                                 int* __restrict__ counter, int n) {
  const int i = blockIdx.x * 256 + threadIdx.x;
  const int lane = threadIdx.x & 63;
  const int c = (i < n) ? counts[i] : 0;
  int pre = c;
#pragma unroll
  for (int m = 1; m < 64; m <<= 1) {
    const int t = __shfl_up(pre, m);
    if (lane >= m) pre += t;
  }
  const int wavesum = __shfl(pre, 63);
  int base = 0;
  if (lane == 0) base = atomicAdd(counter, wavesum);
  base = __shfl(base, 0);
  const int pos = base + pre - c;  // exclusive scan position
  if (i < n) {
    offs[i] = pos;
    cursor[i] = pos;
  }
}

__global__ __launch_bounds__(256) void k_scatter(const int* __restrict__ dst,
                                                 int* __restrict__ cursor,
                                                 int* __restrict__ sorted, int E) {
  const int e = blockIdx.x * 256 + threadIdx.x;
  if (e < E) {
    const int p = atomicAdd(&cursor[clampi(dst[e], 0, NN - 1)], 1);
    if (p >= 0 && p < E) sorted[p] = e;
  }
}

// ---------------- LayerNorm: f32 in -> bf16 out (one wave per row of 256) ----------------
__global__ __launch_bounds__(256) void k_ln(const float* __restrict__ x,
                                            const float* __restrict__ g,
                                            const float* __restrict__ b,
                                            unsigned short* __restrict__ out, int n) {
  const int row = blockIdx.x * 4 + (threadIdx.x >> 6);
  if (row >= n) return;
  const int lane = threadIdx.x & 63;
  float4 xv = *(const float4*)(x + (size_t)row * 256 + 4 * lane);
  float v0 = xv.x, v1 = xv.y, v2 = xv.z, v3 = xv.w;
  float s = v0 + v1 + v2 + v3;
  float ss = v0 * v0 + v1 * v1 + v2 * v2 + v3 * v3;
#pragma unroll
  for (int m = 1; m < 64; m <<= 1) {
    s += __shfl_xor(s, m);
    ss += __shfl_xor(ss, m);
  }
  const float mu = s * (1.f / 256.f);
  const float var = ss * (1.f / 256.f) - mu * mu;
  const float rs = rsqrtf(var + 1e-5f);
  float4 gv = *(const float4*)(g + 4 * lane);
  float4 bv = *(const float4*)(b + 4 * lane);
  ushort4 o;
  o.x = f2b((v0 - mu) * rs * gv.x + bv.x);
  o.y = f2b((v1 - mu) * rs * gv.y + bv.y);
  o.z = f2b((v2 - mu) * rs * gv.z + bv.z);
  o.w = f2b((v3 - mu) * rs * gv.w + bv.w);
  *(ushort4*)(out + (size_t)row * 256 + 4 * lane) = o;
}

// ---------------- attention A: per-edge scores + per-(node,head) max (depth-2 pipeline)
__global__ __launch_bounds__(256) void k_attn_score(
    const float* __restrict__ q, const float* __restrict__ k,
    const float* __restrict__ We, const float* __restrict__ be,
    const int* __restrict__ src, const float* __restrict__ ew,
    const float* __restrict__ ef, const int* __restrict__ offs,
    const int* __restrict__ counts, const int* __restrict__ sorted,
    float* __restrict__ scores, float* __restrict__ mxbuf) {
  __shared__ float WeS[32][36];
  __shared__ float beS[32];
  const int t = threadIdx.x;
  for (int i = t; i < 1024; i += 256) WeS[i >> 5][i & 31] = We[i];
  if (t < 32) beS[t] = be[t];
  __syncthreads();
  const int node = blockIdx.x * 4 + (t >> 6);
  if (node >= NN) return;
  const int lane = t & 63;
  const int h = lane >> 3;
  const int s8 = lane & 7;
  const int d0 = 4 * s8;
  const float scale = 0.17677669529663689f;  // 1/sqrt(32)

  float4 qv = *(const float4*)(q + (size_t)node * 256 + 4 * lane);
  const float qarr[4] = {qv.x, qv.y, qv.z, qv.w};

  float w0 = 0.f, w1 = 0.f, w2 = 0.f, w3 = 0.f, qb = 0.f;
#pragma unroll
  for (int t8 = 0; t8 < 8; ++t8) {
#pragma unroll
    for (int u = 0; u < 4; ++u) {
      const float qj = __shfl(qarr[u], 8 * h + t8);
      const int j = 4 * t8 + u;
      w0 += qj * WeS[j][d0 + 0];
      w1 += qj * WeS[j][d0 + 1];
      w2 += qj * WeS[j][d0 + 2];
      w3 += qj * WeS[j][d0 + 3];
      qb += qj * beS[j];
    }
  }

  const int beg = clampi(offs[node], 0, NE);
  const int cnt = clampi(counts[node], 0, NE - beg);

  float mx = -3.0e38f;
  for (int c = 0; c < cnt; c += 64) {
    const int ccnt = min(64, cnt - c);
    int eid_l = 0, s_l = 0;
    float ew_l = 0.f;
    if (lane < ccnt) {
      eid_l = clampi(sorted[beg + c + lane], 0, NE - 1);
      s_l = clampi(src[eid_l], 0, NN - 1);
      ew_l = ew[eid_l];
    }
    float4 kb0 = {0, 0, 0, 0}, kb1 = {0, 0, 0, 0};
    float4 eb0 = {0, 0, 0, 0}, eb1 = {0, 0, 0, 0};
    {
      const int s0 = rdl_i(s_l, 0), e0 = rdl_i(eid_l, 0);
      kb0 = *(const float4*)(k + (size_t)s0 * 256 + 4 * lane);
      eb0 = *(const float4*)(ef + (size_t)e0 * 32 + d0);
    }
    if (ccnt > 1) {
      const int s1 = rdl_i(s_l, 1), e1 = rdl_i(eid_l, 1);
      kb1 = *(const float4*)(k + (size_t)s1 * 256 + 4 * lane);
      eb1 = *(const float4*)(ef + (size_t)e1 * 32 + d0);
    }
    for (int j = 0; j < ccnt; ++j) {
      float4 kn = kb1, en = eb1;
      if (j + 2 < ccnt) {
        const int sn = rdl_i(s_l, j + 2), enid = rdl_i(eid_l, j + 2);
        kn = *(const float4*)(k + (size_t)sn * 256 + 4 * lane);
        en = *(const float4*)(ef + (size_t)enid * 32 + d0);
      }
      const float wgt = rdl_f(ew_l, j);
      const int eid = rdl_i(eid_l, j);
      float p = qv.x * kb0.x + qv.y * kb0.y + qv.z * kb0.z + qv.w * kb0.w +
                w0 * eb0.x + w1 * eb0.y + w2 * eb0.z + w3 * eb0.w;
      p += __shfl_xor(p, 1);
      p += __shfl_xor(p, 2);
      p += __shfl_xor(p, 4);
      const float scr = (p + qb) * scale * wgt;
      mx = fmaxf(mx, scr);
      if (s8 == 0) scores[(size_t)eid * 8 + h] = scr;
      kb0 = kb1; eb0 = eb1; kb1 = kn; eb1 = en;
    }
  }
  if (s8 == 0) mxbuf[(size_t)node * 8 + h] = mx;
}

// ---------------- attention B: exp/sum + V aggregation; stores inv for k_norm
__global__ __launch_bounds__(256) void k_attn_agg(
    const unsigned short* __restrict__ v, const int* __restrict__ src,
    const int* __restrict__ offs, const int* __restrict__ counts,
    const int* __restrict__ sorted, const float* __restrict__ scores,
    const float* __restrict__ mxbuf, float* __restrict__ invbuf,
    unsigned short* __restrict__ agg) {
  const int node = blockIdx.x * 4 + (threadIdx.x >> 6);
  if (node >= NN) return;
  const int lane = threadIdx.x & 63;
  const int h = lane >> 3;
  const int s8 = lane & 7;

  const int beg = clampi(offs[node], 0, NE);
  const int cnt = clampi(counts[node], 0, NE - beg);
  const float mx = mxbuf[(size_t)node * 8 + h];

  float a0 = 0.f, a1 = 0.f, a2 = 0.f, a3 = 0.f, ssum = 0.f;
  for (int c = 0; c < cnt; c += 64) {
    const int ccnt = min(64, cnt - c);
    int eid_l = 0, s_l = 0;
    if (lane < ccnt) {
      eid_l = clampi(sorted[beg + c + lane], 0, NE - 1);
      s_l = clampi(src[eid_l], 0, NN - 1);
    }
    ushort4 vb0 = {0, 0, 0, 0}, vb1 = {0, 0, 0, 0};
    float sc0 = 0.f, sc1 = 0.f;
    {
      const int s0 = rdl_i(s_l, 0), e0 = rdl_i(eid_l, 0);
      vb0 = *(const ushort4*)(v + (size_t)s0 * 256 + 4 * lane);
      sc0 = scores[(size_t)e0 * 8 + h];
    }
    if (ccnt > 1) {
      const int s1 = rdl_i(s_l, 1), e1 = rdl_i(eid_l, 1);
      vb1 = *(const ushort4*)(v + (size_t)s1 * 256 + 4 * lane);
      sc1 = scores[(size_t)e1 * 8 + h];
    }
    for (int j = 0; j < ccnt; ++j) {
      ushort4 vn = vb1;
      float scn = sc1;
      if (j + 2 < ccnt) {
        const int sn = rdl_i(s_l, j + 2), enid = rdl_i(eid_l, j + 2);
        vn = *(const ushort4*)(v + (size_t)sn * 256 + 4 * lane);
        scn = scores[(size_t)enid * 8 + h];
      }
      const float e = __expf(sc0 - mx);
      ssum += e;
      union { unsigned u; float f; } c0, c1, c2, c3;
      c0.u = ((unsigned)vb0.x) << 16; c1.u = ((unsigned)vb0.y) << 16;
      c2.u = ((unsigned)vb0.z) << 16; c3.u = ((unsigned)vb0.w) << 16;
      a0 += e * c0.f; a1 += e * c1.f; a2 += e * c2.f; a3 += e * c3.f;
      vb0 = vb1; sc0 = sc1; vb1 = vn; sc1 = scn;
    }
  }
  const float inv = (cnt > 0) ? 1.f / ssum : 0.f;
  ushort4 o;
  o.x = f2b(a0 * inv); o.y = f2b(a1 * inv); o.z = f2b(a2 * inv); o.w = f2b(a3 * inv);
  *(ushort4*)(agg + (size_t)node * 256 + 4 * lane) = o;
  if (s8 == 0) invbuf[(size_t)node * 8 + h] = inv;  // inv is uniform across the 8-lane group
}

// ---------------- flat per-(edge,head) weight normalization, in place.
__global__ __launch_bounds__(256) void k_norm(const int* __restrict__ dst,
                                              const float* __restrict__ mxbuf,
                                              const float* __restrict__ invbuf,
                                              float* __restrict__ scores) {
  const int idx = blockIdx.x * 256 + threadIdx.x;  // (e,h): e = idx>>3, h = idx&7
  if (idx >= NE * 8) return;
  const int e = idx >> 3;
  const int h = idx & 7;
  const int node = clampi(dst[e], 0, NN - 1);
  const float mx = mxbuf[(size_t)node * 8 + h];
  const float inv = invbuf[(size_t)node * 8 + h];
  scores[idx] = __expf(scores[idx] - mx) * inv;  // same thread reads+writes idx
}

// ---------------- NT GEMM, double-buffered LDS + T2 XOR-swizzle (bf16 MFMA, f32 epilogue)
// out[m,c] = epi(sum_k A[m,k]*W[c,k] + bias[c])
// 2-phase pipeline (T3 minimal recipe): STAGE(buf^1, t+1) issued BEFORE the
// ds_read+MFMA of buf, so the end-of-iteration __syncthreads (vmcnt0 drain)
// only pays the residual load latency instead of the full HBM/L3 latency.
// Safety: stage writes buf^1, compute reads buf -> disjoint; end barrier
// (lgkmcnt0 + vmcnt0 + workgroup sync) orders buffer reuse. LDS 64KB.
// Swizzle per rule 21: linear LDS dest, inverse-swizzled global src col,
// same XOR on the ds_read address. K-order identical -> bitwise-same results.
// epi 0: bf16 store | 1: f32 store | 2: f32 outf[o]=resf[o]+sc*f | 3: bf16 gelu store
__global__ __launch_bounds__(256) void k_gemm(
    const unsigned short* __restrict__ A, const unsigned short* __restrict__ W,
    const float* __restrict__ bias, int M, int NC, int K, int epi,
    unsigned short* __restrict__ outb, float* __restrict__ outf,
    const float* __restrict__ resf, const float* __restrict__ scal) {
  __shared__ unsigned short As[2][128 * 64];
  __shared__ unsigned short Bs[2][128 * 64];
  const int t = threadIdx.x;
  const int lane = t & 63;
  const int wv = t >> 6;
  const int wr = wv >> 1;        // wave row (0..1) -> 64 M-rows
  const int wc = wv & 1;         // wave col (0..1) -> 64 NC-cols
  const int m0 = blockIdx.x * 128;
  const int c0 = blockIdx.y * 128;
  const int r16 = lane & 15;
  const int quad = lane >> 4;

  f32x4 acc[4][4];
#pragma unroll
  for (int i = 0; i < 4; ++i)
#pragma unroll
    for (int j = 0; j < 4; ++j) acc[i][j] = {0.f, 0.f, 0.f, 0.f};

  // staging geometry (constant): lane's linear LDS slot within the 16KB tile
  // o = wv*1024 + i*4096 + lane*16 ; row = o>>7 ; colb = (o&127) ^ ((row&7)<<4)
  // prologue: stage K-tile 0 into buffer 0
#pragma unroll
  for (int i = 0; i < 4; ++i) {
    const int ob = wv * 1024 + i * 4096;
    const int o = ob + lane * 16;
    const int row = o >> 7;
    const int colb = (o & 127) ^ ((row & 7) << 4);
    const int ra = (m0 + row < M) ? (m0 + row) : (M - 1);  // tail clamp (stores guarded)
    gl_lds16((const char*)A + ((size_t)ra * K) * 2 + colb, (char*)As[0] + ob);
    gl_lds16((const char*)W + ((size_t)(c0 + row) * K) * 2 + colb, (char*)Bs[0] + ob);
  }
  __syncthreads();

  const int nt = K >> 6;
  for (int tt = 0; tt < nt; ++tt) {
    const int cur = tt & 1;
    if (tt + 1 < nt) {  // issue next-tile stage before compute (overlap)
      const int k0 = (tt + 1) << 6;
#pragma unroll
      for (int i = 0; i < 4; ++i) {
        const int ob = wv * 1024 + i * 4096;
        const int o = ob + lane * 16;
        const int row = o >> 7;
        const int colb = (o & 127) ^ ((row & 7) << 4);
        const int ra = (m0 + row < M) ? (m0 + row) : (M - 1);
        gl_lds16((const char*)A + ((size_t)ra * K + k0) * 2 + colb, (char*)As[cur ^ 1] + ob);
        gl_lds16((const char*)W + ((size_t)(c0 + row) * K + k0) * 2 + colb, (char*)Bs[cur ^ 1] + ob);
      }
    }
#pragma unroll
    for (int kk = 0; kk < 64; kk += 32) {
      s16x8 a[4], b[4];
#pragma unroll
      for (int i = 0; i < 4; ++i) {
        const int row = wr * 64 + 16 * i + r16;
        const int cb = (kk + quad * 8) * 2;
        a[i] = *(const s16x8*)((const char*)As[cur] + row * 128 + (cb ^ ((row & 7) << 4)));
      }
#pragma unroll
      for (int j = 0; j < 4; ++j) {
        const int row = wc * 64 + 16 * j + r16;
        const int cb = (kk + quad * 8) * 2;
        b[j] = *(const s16x8*)((const char*)Bs[cur] + row * 128 + (cb ^ ((row & 7) << 4)));
      }
#pragma unroll
      for (int i = 0; i < 4; ++i)
#pragma unroll
        for (int j = 0; j < 4; ++j)
          acc[i][j] = __builtin_amdgcn_mfma_f32_16x16x32_bf16(a[i], b[j], acc[i][j], 0, 0, 0);
    }
    __syncthreads();  // drains this wave's lgkm (reads of cur) + vmcnt (stage of next)
  }

  const float sc = scal ? scal[0] : 0.f;
#pragma unroll
  for (int j = 0; j < 4; ++j) {
    const int c = c0 + wc * 64 + 16 * j + r16;
    const float bc = bias[c];
#pragma unroll
    for (int i = 0; i < 4; ++i) {
#pragma unroll
      for (int r = 0; r < 4; ++r) {
        const int m = m0 + wr * 64 + 16 * i + quad * 4 + r;
        if (m < M) {
          float f = acc[i][j][r] + bc;
          const size_t o = (size_t)m * NC + c;
          if (epi == 0) {
            outb[o] = f2b(f);
          } else if (epi == 1) {
            outf[o] = f;
          } else if (epi == 2) {
            outf[o] = resf[o] + sc * f;  // same thread reads+writes o (in-place safe)
          } else {
            outb[o] = f2b(0.5f * f * (1.f + erff(f * 0.70710678118654752f)));
          }
        }
      }
    }
  }
}

extern "C" void kernel_launch(void* const* d_in, const int* in_sizes, int n_in,
                              void* d_out, int out_size, void* d_ws, size_t ws_size,
                              hipStream_t stream) {
  (void)in_sizes; (void)n_in; (void)out_size; (void)ws_size;
  const float* x   = (const float*)d_in[0];
  const int* ei    = (const int*)d_in[1];
  const float* ef  = (const float*)d_in[2];
  const float* ew  = (const float*)d_in[3];
  const float* Wq  = (const float*)d_in[4];
  const float* bq  = (const float*)d_in[5];
  const float* Wk  = (const float*)d_in[6];
  const float* bk  = (const float*)d_in[7];
  const float* Wv  = (const float*)d_in[8];
  const float* bv  = (const float*)d_in[9];
  const float* We  = (const float*)d_in[10];
  const float* bel = (const float*)d_in[11];
  const float* Wo  = (const float*)d_in[12];
  const float* bo  = (const float*)d_in[13];
  const float* W1  = (const float*)d_in[14];
  const float* b1  = (const float*)d_in[15];
  const float* W2  = (const float*)d_in[16];
  const float* b2  = (const float*)d_in[17];
  const float* g1  = (const float*)d_in[18];
  const float* be1 = (const float*)d_in[19];
  const float* g2  = (const float*)d_in[20];
  const float* be2 = (const float*)d_in[21];
  const float* alpha = (const float*)d_in[22];
  const float* beta  = (const float*)d_in[23];

  // ---- workspace (~166 MB), small index arrays first ----
  char* w = (char*)d_ws;
  auto alloc = [&](size_t b) { char* p = w; w += (b + 255) & ~(size_t)255; return p; };

  int* counts          = (int*)alloc((size_t)(NN + 1) * 4);   // counts[NN] = global cursor
  int* offs            = (int*)alloc((size_t)NN * 4);
  int* cursor          = (int*)alloc((size_t)NN * 4);
  int* sorted          = (int*)alloc((size_t)NE * 4);
  float* mxbuf         = (float*)alloc((size_t)NN * 8 * 4);
  float* invbuf        = (float*)alloc((size_t)NN * 8 * 4);
  unsigned short* wbf  = (unsigned short*)alloc((size_t)786432 * 2);   // bf16 weights pool
  unsigned short* xn   = (unsigned short*)alloc((size_t)NN * 256 * 2); // agg aliases xn
  float* qf            = (float*)alloc((size_t)NN * 256 * 4);          // h1 = qf..kf (102.4MB bf16)
  float* kf            = (float*)alloc((size_t)NN * 256 * 4);          // contiguous after qf
  unsigned short* vb   = (unsigned short*)alloc((size_t)NN * 256 * 2); // xn2 aliases vb

  unsigned short* wq_bf = wbf;
  unsigned short* wk_bf = wbf + 65536;
  unsigned short* wv_bf = wbf + 131072;
  unsigned short* wo_bf = wbf + 196608;
  unsigned short* w1_bf = wbf + 262144;
  unsigned short* w2_bf = wbf + 524288;

  unsigned short* agg = xn;   // xn dead after QKV GEMMs
  unsigned short* xn2 = vb;   // vb dead after k_attn_agg
  unsigned short* h1  = (unsigned short*)qf;  // qf+kf dead after attention: [N,1024] bf16

  float* out_x   = (float*)d_out;                         // also serves as x_mid (in-place epi-2)
  float* scores  = (float*)d_out + (size_t)NN * 256;      // [E,8] f32 -> becomes attn weights in place

  const int* src = ei;
  const int* dst = ei + NE;

  hipMemsetAsync(counts, 0, (size_t)(NN + 1) * 4, stream);
  k_count<<<dim3((NE + 255) / 256), dim3(256), 0, stream>>>(dst, counts, NE);
  k_reserve<<<dim3((NN + 255) / 256), dim3(256), 0, stream>>>(counts, offs, cursor, counts + NN, NN);
  k_scatter<<<dim3((NE + 255) / 256), dim3(256), 0, stream>>>(dst, cursor, sorted, NE);

  // weight conversions f32 -> bf16
  k_cvt<<<dim3(256), dim3(256), 0, stream>>>(Wq, wq_bf, 65536);
  k_cvt<<<dim3(256), dim3(256), 0, stream>>>(Wk, wk_bf, 65536);
  k_cvt<<<dim3(256), dim3(256), 0, stream>>>(Wv, wv_bf, 65536);
  k_cvt<<<dim3(256), dim3(256), 0, stream>>>(Wo, wo_bf, 65536);
  k_cvt<<<dim3(1024), dim3(256), 0, stream>>>(W1, w1_bf, 262144);
  k_cvt<<<dim3(1024), dim3(256), 0, stream>>>(W2, w2_bf, 262144);

  k_ln<<<dim3(NN / 4), dim3(256), 0, stream>>>(x, g1, be1, xn, NN);

  dim3 gB(256);
  dim3 gQ((NN + 127) / 128, 2);   // NC=256 tiles
  dim3 gF1((NN + 127) / 128, 8);  // NC=1024 tiles
  // q,k as f32 (precision-critical for scores); v as bf16 (feeds bf16 aggregation)
  k_gemm<<<gQ, gB, 0, stream>>>(xn, wq_bf, bq, NN, 256, 256, 1, nullptr, qf, nullptr, nullptr);
  k_gemm<<<gQ, gB, 0, stream>>>(xn, wk_bf, bk, NN, 256, 256, 1, nullptr, kf, nullptr, nullptr);
  k_gemm<<<gQ, gB, 0, stream>>>(xn, wv_bf, bv, NN, 256, 256, 0, vb, nullptr, nullptr, nullptr);

  k_attn_score<<<dim3(NN / 4), dim3(256), 0, stream>>>(qf, kf, We, bel, src, ew, ef,
                                                       offs, counts, sorted, scores, mxbuf);
  k_attn_agg<<<dim3(NN / 4), dim3(256), 0, stream>>>(vb, src, offs, counts, sorted,
                                                     scores, mxbuf, invbuf, agg);
  k_norm<<<dim3((NE * 8 + 255) / 256), dim3(256), 0, stream>>>(dst, mxbuf, invbuf, scores);

  // x_mid (= d_out x-half) = x + alpha*(agg @ Wo^T + bo)
  k_gemm<<<gQ, gB, 0, stream>>>(agg, wo_bf, bo, NN, 256, 256, 2, nullptr, out_x, x, alpha);

  k_ln<<<dim3(NN / 4), dim3(256), 0, stream>>>(out_x, g2, be2, xn2, NN);

  // h1 = gelu(xn2 @ W1^T + b1)  (bf16, overwrites qf..kf)
  k_gemm<<<gF1, gB, 0, stream>>>(xn2, w1_bf, b1, NN, 1024, 256, 3, h1, nullptr, nullptr, nullptr);

  // out_x = x_mid + beta*(h1 @ W2^T + b2)   (in-place per-element)
  k_gemm<<<gQ, gB, 0, stream>>>(h1, w2_bf, b2, NN, 256, 1024, 2, nullptr, out_x, out_x, beta);
}

// Round 7
// 1544.010 us; speedup vs baseline: 1.0174x; 1.0174x over previous
//
#include <hip/hip_runtime.h>

typedef short s16x8 __attribute__((ext_vector_type(8)));
typedef float f32x4 __attribute__((ext_vector_type(4)));

static constexpr int NN = 50000;
static constexpr int NE = 1600000;

__device__ __forceinline__ unsigned short f2b(float f) {
  union { float f; unsigned u; } c; c.f = f;
  unsigned x = c.u;
  x += 0x7fffu + ((x >> 16) & 1u);
  return (unsigned short)(x >> 16);
}
__device__ __forceinline__ int clampi(int v, int lo, int hi) {
  return v < lo ? lo : (v > hi ? hi : v);
}
__device__ __forceinline__ int rdl_i(int v, int l) {
  return __builtin_amdgcn_readlane(v, l);
}
__device__ __forceinline__ float rdl_f(float v, int l) {
  union { float f; int i; } c; c.f = v;
  c.i = __builtin_amdgcn_readlane(c.i, l);
  return c.f;
}
// global -> LDS direct copy, 16B per lane. LDS dest is wave-uniform base;
// HW writes base + lane*16. Global src is per-lane.
__device__ __forceinline__ void gl_lds16(const void* g, void* l) {
  __builtin_amdgcn_global_load_lds((const __attribute__((address_space(1))) void*)g,
                                   (__attribute__((address_space(3))) void*)l, 16, 0, 0);
}

// ---------------- all weight conversions f32 -> bf16 + QKV bias concat, ONE launch
// wbf layout: [0,64K)=Wq [64K,128K)=Wk [128K,192K)=Wv [192K,256K)=Wo
//             [256K,512K)=W1 [512K,768K)=W2 ; then 768 floats bqkv = bq|bk|bv
__global__ __launch_bounds__(256) void k_cvt_all(
    const float* __restrict__ Wq, const float* __restrict__ Wk,
    const float* __restrict__ Wv, const float* __restrict__ Wo,
    const float* __restrict__ W1, const float* __restrict__ W2,
    const float* __restrict__ bq, const float* __restrict__ bk,
    const float* __restrict__ bv, unsigned short* __restrict__ wbf,
    float* __restrict__ bqkv) {
  const int i = blockIdx.x * 256 + threadIdx.x;
  if (i < 786432) {
    float v;
    if (i < 65536) v = Wq[i];
    else if (i < 131072) v = Wk[i - 65536];
    else if (i < 196608) v = Wv[i - 131072];
    else if (i < 262144) v = Wo[i - 196608];
    else if (i < 524288) v = W1[i - 262144];
    else v = W2[i - 524288];
    wbf[i] = f2b(v);
  } else if (i < 786432 + 768) {
    const int j = i - 786432;
    bqkv[j] = (j < 256) ? bq[j] : (j < 512 ? bk[j - 256] : bv[j - 512]);
  }
}

// ---------------- CSR build ----------------
__global__ __launch_bounds__(256) void k_count(const int* __restrict__ dst,
                                               int* __restrict__ counts, int E) {
  const int e = blockIdx.x * 256 + threadIdx.x;
  if (e < E) atomicAdd(&counts[clampi(dst[e], 0, NN - 1)], 1);
}

// wave-scan reserve: one atomic per wave instead of 50000 same-address atomics.
__global__ __launch_bounds__(256) void k_reserve(const int* __restrict__ counts,
                                                 int* __restrict__ offs,
                                                 int* __restrict__ cursor,
                                                 int* __restrict__ counter, int n) {
  const int i = blockIdx.x * 256 + threadIdx.x;
  const int lane = threadIdx.x & 63;
  const int c = (i < n) ? counts[i] : 0;
  int pre = c;
#pragma unroll
  for (int m = 1; m < 64; m <<= 1) {
    const int t = __shfl_up(pre, m);
    if (lane >= m) pre += t;
  }
  const int wavesum = __shfl(pre, 63);
  int base = 0;
  if (lane == 0) base = atomicAdd(counter, wavesum);
  base = __shfl(base, 0);
  const int pos = base + pre - c;  // exclusive scan position
  if (i < n) {
    offs[i] = pos;
    cursor[i] = pos;
  }
}

__global__ __launch_bounds__(256) void k_scatter(const int* __restrict__ dst,
                                                 int* __restrict__ cursor,
                                                 int* __restrict__ sorted, int E) {
  const int e = blockIdx.x * 256 + threadIdx.x;
  if (e < E) {
    const int p = atomicAdd(&cursor[clampi(dst[e], 0, NN - 1)], 1);
    if (p >= 0 && p < E) sorted[p] = e;
  }
}

// ---------------- LayerNorm: f32 in -> bf16 out (one wave per row of 256) ----------------
__global__ __launch_bounds__(256) void k_ln(const float* __restrict__ x,
                                            const float* __restrict__ g,
                                            const float* __restrict__ b,
                                            unsigned short* __restrict__ out, int n) {
  const int row = blockIdx.x * 4 + (threadIdx.x >> 6);
  if (row >= n) return;
  const int lane = threadIdx.x & 63;
  float4 xv = *(const float4*)(x + (size_t)row * 256 + 4 * lane);
  float v0 = xv.x, v1 = xv.y, v2 = xv.z, v3 = xv.w;
  float s = v0 + v1 + v2 + v3;
  float ss = v0 * v0 + v1 * v1 + v2 * v2 + v3 * v3;
#pragma unroll
  for (int m = 1; m < 64; m <<= 1) {
    s += __shfl_xor(s, m);
    ss += __shfl_xor(ss, m);
  }
  const float mu = s * (1.f / 256.f);
  const float var = ss * (1.f / 256.f) - mu * mu;
  const float rs = rsqrtf(var + 1e-5f);
  float4 gv = *(const float4*)(g + 4 * lane);
  float4 bv = *(const float4*)(b + 4 * lane);
  ushort4 o;
  o.x = f2b((v0 - mu) * rs * gv.x + bv.x);
  o.y = f2b((v1 - mu) * rs * gv.y + bv.y);
  o.z = f2b((v2 - mu) * rs * gv.z + bv.z);
  o.w = f2b((v3 - mu) * rs * gv.w + bv.w);
  *(ushort4*)(out + (size_t)row * 256 + 4 * lane) = o;
}

// ---------------- attention A: per-edge scores + per-(node,head) max (depth-2 pipeline)
__global__ __launch_bounds__(256) void k_attn_score(
    const float* __restrict__ q, const float* __restrict__ k,
    const float* __restrict__ We, const float* __restrict__ be,
    const int* __restrict__ src, const float* __restrict__ ew,
    const float* __restrict__ ef, const int* __restrict__ offs,
    const int* __restrict__ counts, const int* __restrict__ sorted,
    float* __restrict__ scores, float* __restrict__ mxbuf) {
  __shared__ float WeS[32][36];
  __shared__ float beS[32];
  const int t = threadIdx.x;
  for (int i = t; i < 1024; i += 256) WeS[i >> 5][i & 31] = We[i];
  if (t < 32) beS[t] = be[t];
  __syncthreads();
  const int node = blockIdx.x * 4 + (t >> 6);
  if (node >= NN) return;
  const int lane = t & 63;
  const int h = lane >> 3;
  const int s8 = lane & 7;
  const int d0 = 4 * s8;
  const float scale = 0.17677669529663689f;  // 1/sqrt(32)

  float4 qv = *(const float4*)(q + (size_t)node * 256 + 4 * lane);
  const float qarr[4] = {qv.x, qv.y, qv.z, qv.w};

  float w0 = 0.f, w1 = 0.f, w2 = 0.f, w3 = 0.f, qb = 0.f;
#pragma unroll
  for (int t8 = 0; t8 < 8; ++t8) {
#pragma unroll
    for (int u = 0; u < 4; ++u) {
      const float qj = __shfl(qarr[u], 8 * h + t8);
      const int j = 4 * t8 + u;
      w0 += qj * WeS[j][d0 + 0];
      w1 += qj * WeS[j][d0 + 1];
      w2 += qj * WeS[j][d0 + 2];
      w3 += qj * WeS[j][d0 + 3];
      qb += qj * beS[j];
    }
  }

  const int beg = clampi(offs[node], 0, NE);
  const int cnt = clampi(counts[node], 0, NE - beg);

  float mx = -3.0e38f;
  for (int c = 0; c < cnt; c += 64) {
    const int ccnt = min(64, cnt - c);
    int eid_l = 0, s_l = 0;
    float ew_l = 0.f;
    if (lane < ccnt) {
      eid_l = clampi(sorted[beg + c + lane], 0, NE - 1);
      s_l = clampi(src[eid_l], 0, NN - 1);
      ew_l = ew[eid_l];
    }
    float4 kb0 = {0, 0, 0, 0}, kb1 = {0, 0, 0, 0};
    float4 eb0 = {0, 0, 0, 0}, eb1 = {0, 0, 0, 0};
    {
      const int s0 = rdl_i(s_l, 0), e0 = rdl_i(eid_l, 0);
      kb0 = *(const float4*)(k + (size_t)s0 * 256 + 4 * lane);
      eb0 = *(const float4*)(ef + (size_t)e0 * 32 + d0);
    }
    if (ccnt > 1) {
      const int s1 = rdl_i(s_l, 1), e1 = rdl_i(eid_l, 1);
      kb1 = *(const float4*)(k + (size_t)s1 * 256 + 4 * lane);
      eb1 = *(const float4*)(ef + (size_t)e1 * 32 + d0);
    }
    for (int j = 0; j < ccnt; ++j) {
      float4 kn = kb1, en = eb1;
      if (j + 2 < ccnt) {
        const int sn = rdl_i(s_l, j + 2), enid = rdl_i(eid_l, j + 2);
        kn = *(const float4*)(k + (size_t)sn * 256 + 4 * lane);
        en = *(const float4*)(ef + (size_t)enid * 32 + d0);
      }
      const float wgt = rdl_f(ew_l, j);
      const int eid = rdl_i(eid_l, j);
      float p = qv.x * kb0.x + qv.y * kb0.y + qv.z * kb0.z + qv.w * kb0.w +
                w0 * eb0.x + w1 * eb0.y + w2 * eb0.z + w3 * eb0.w;
      p += __shfl_xor(p, 1);
      p += __shfl_xor(p, 2);
      p += __shfl_xor(p, 4);
      const float scr = (p + qb) * scale * wgt;
      mx = fmaxf(mx, scr);
      if (s8 == 0) scores[(size_t)eid * 8 + h] = scr;
      kb0 = kb1; eb0 = eb1; kb1 = kn; eb1 = en;
    }
  }
  if (s8 == 0) mxbuf[(size_t)node * 8 + h] = mx;
}

// ---------------- attention B: exp/sum + V aggregation; stores inv for k_norm
__global__ __launch_bounds__(256) void k_attn_agg(
    const unsigned short* __restrict__ v, const int* __restrict__ src,
    const int* __restrict__ offs, const int* __restrict__ counts,
    const int* __restrict__ sorted, const float* __restrict__ scores,
    const float* __restrict__ mxbuf, float* __restrict__ invbuf,
    unsigned short* __restrict__ agg) {
  const int node = blockIdx.x * 4 + (threadIdx.x >> 6);
  if (node >= NN) return;
  const int lane = threadIdx.x & 63;
  const int h = lane >> 3;
  const int s8 = lane & 7;

  const int beg = clampi(offs[node], 0, NE);
  const int cnt = clampi(counts[node], 0, NE - beg);
  const float mx = mxbuf[(size_t)node * 8 + h];

  float a0 = 0.f, a1 = 0.f, a2 = 0.f, a3 = 0.f, ssum = 0.f;
  for (int c = 0; c < cnt; c += 64) {
    const int ccnt = min(64, cnt - c);
    int eid_l = 0, s_l = 0;
    if (lane < ccnt) {
      eid_l = clampi(sorted[beg + c + lane], 0, NE - 1);
      s_l = clampi(src[eid_l], 0, NN - 1);
    }
    ushort4 vb0 = {0, 0, 0, 0}, vb1 = {0, 0, 0, 0};
    float sc0 = 0.f, sc1 = 0.f;
    {
      const int s0 = rdl_i(s_l, 0), e0 = rdl_i(eid_l, 0);
      vb0 = *(const ushort4*)(v + (size_t)s0 * 256 + 4 * lane);
      sc0 = scores[(size_t)e0 * 8 + h];
    }
    if (ccnt > 1) {
      const int s1 = rdl_i(s_l, 1), e1 = rdl_i(eid_l, 1);
      vb1 = *(const ushort4*)(v + (size_t)s1 * 256 + 4 * lane);
      sc1 = scores[(size_t)e1 * 8 + h];
    }
    for (int j = 0; j < ccnt; ++j) {
      ushort4 vn = vb1;
      float scn = sc1;
      if (j + 2 < ccnt) {
        const int sn = rdl_i(s_l, j + 2), enid = rdl_i(eid_l, j + 2);
        vn = *(const ushort4*)(v + (size_t)sn * 256 + 4 * lane);
        scn = scores[(size_t)enid * 8 + h];
      }
      const float e = __expf(sc0 - mx);
      ssum += e;
      union { unsigned u; float f; } c0, c1, c2, c3;
      c0.u = ((unsigned)vb0.x) << 16; c1.u = ((unsigned)vb0.y) << 16;
      c2.u = ((unsigned)vb0.z) << 16; c3.u = ((unsigned)vb0.w) << 16;
      a0 += e * c0.f; a1 += e * c1.f; a2 += e * c2.f; a3 += e * c3.f;
      vb0 = vb1; sc0 = sc1; vb1 = vn; sc1 = scn;
    }
  }
  const float inv = (cnt > 0) ? 1.f / ssum : 0.f;
  ushort4 o;
  o.x = f2b(a0 * inv); o.y = f2b(a1 * inv); o.z = f2b(a2 * inv); o.w = f2b(a3 * inv);
  *(ushort4*)(agg + (size_t)node * 256 + 4 * lane) = o;
  if (s8 == 0) invbuf[(size_t)node * 8 + h] = inv;  // inv is uniform across the 8-lane group
}

// ---------------- flat per-(edge,head) weight normalization, in place.
__global__ __launch_bounds__(256) void k_norm(const int* __restrict__ dst,
                                              const float* __restrict__ mxbuf,
                                              const float* __restrict__ invbuf,
                                              float* __restrict__ scores) {
  const int idx = blockIdx.x * 256 + threadIdx.x;  // (e,h): e = idx>>3, h = idx&7
  if (idx >= NE * 8) return;
  const int e = idx >> 3;
  const int h = idx & 7;
  const int node = clampi(dst[e], 0, NN - 1);
  const float mx = mxbuf[(size_t)node * 8 + h];
  const float inv = invbuf[(size_t)node * 8 + h];
  scores[idx] = __expf(scores[idx] - mx) * inv;  // same thread reads+writes idx
}

// ---------------- NT GEMM, LDS-staged with T2 XOR-swizzle (bf16 MFMA, f32 epilogue)
// out[m,c] = epi(sum_k A[m,k]*W[c,k] + bias[c])
// Block: 256 threads = 4 waves in 2x2 over a 128(M) x 128(NC) tile. BK=64.
// Single-buffer (R5 form: dbuf regressed in R6 - occupancy loss > overlap gain).
// Swizzle per rule 21: linear LDS dest, inverse-swizzled global src col,
// same XOR on the ds_read address. K-order identical -> bitwise-same results.
// epi 0: bf16 store | 1: f32 store | 2: f32 outf[o]=resf[o]+sc*f | 3: bf16 gelu
// epi 4: merged QKV: c<256 -> outf(q) f32, c<512 -> outf+M*256(k) f32, else outb(v) bf16
__global__ __launch_bounds__(256) void k_gemm(
    const unsigned short* __restrict__ A, const unsigned short* __restrict__ W,
    const float* __restrict__ bias, int M, int NC, int K, int epi,
    unsigned short* __restrict__ outb, float* __restrict__ outf,
    const float* __restrict__ resf, const float* __restrict__ scal) {
  __shared__ unsigned short As[128 * 64];
  __shared__ unsigned short Bs[128 * 64];
  const int t = threadIdx.x;
  const int lane = t & 63;
  const int wv = t >> 6;
  const int wr = wv >> 1;        // wave row (0..1) -> 64 M-rows
  const int wc = wv & 1;         // wave col (0..1) -> 64 NC-cols
  const int m0 = blockIdx.x * 128;
  const int c0 = blockIdx.y * 128;
  const int r16 = lane & 15;
  const int quad = lane >> 4;

  f32x4 acc[4][4];
#pragma unroll
  for (int i = 0; i < 4; ++i)
#pragma unroll
    for (int j = 0; j < 4; ++j) acc[i][j] = {0.f, 0.f, 0.f, 0.f};

  for (int k0 = 0; k0 < K; k0 += 64) {
#pragma unroll
    for (int i = 0; i < 4; ++i) {
      const int ob = wv * 1024 + i * 4096;       // wave-uniform LDS base (bytes)
      const int o = ob + lane * 16;              // this lane's linear LDS slot (bytes)
      const int row = o >> 7;
      const int colb = (o & 127) ^ ((row & 7) << 4);  // inverse-swizzled source col
      const int ra = (m0 + row < M) ? (m0 + row) : (M - 1);  // tail clamp (stores guarded)
      gl_lds16((const char*)A + ((size_t)ra * K + k0) * 2 + colb, (char*)As + ob);
      gl_lds16((const char*)W + ((size_t)(c0 + row) * K + k0) * 2 + colb, (char*)Bs + ob);
    }
    __syncthreads();
#pragma unroll
    for (int kk = 0; kk < 64; kk += 32) {
      s16x8 a[4], b[4];
#pragma unroll
      for (int i = 0; i < 4; ++i) {
        const int row = wr * 64 + 16 * i + r16;
        const int cb = (kk + quad * 8) * 2;
        a[i] = *(const s16x8*)((const char*)As + row * 128 + (cb ^ ((row & 7) << 4)));
      }
#pragma unroll
      for (int j = 0; j < 4; ++j) {
        const int row = wc * 64 + 16 * j + r16;
        const int cb = (kk + quad * 8) * 2;
        b[j] = *(const s16x8*)((const char*)Bs + row * 128 + (cb ^ ((row & 7) << 4)));
      }
#pragma unroll
      for (int i = 0; i < 4; ++i)
#pragma unroll
        for (int j = 0; j < 4; ++j)
          acc[i][j] = __builtin_amdgcn_mfma_f32_16x16x32_bf16(a[i], b[j], acc[i][j], 0, 0, 0);
    }
    __syncthreads();
  }

  const float sc = scal ? scal[0] : 0.f;
#pragma unroll
  for (int j = 0; j < 4; ++j) {
    const int c = c0 + wc * 64 + 16 * j + r16;
    const float bc = bias[c];
#pragma unroll
    for (int i = 0; i < 4; ++i) {
#pragma unroll
      for (int r = 0; r < 4; ++r) {
        const int m = m0 + wr * 64 + 16 * i + quad * 4 + r;
        if (m < M) {
          float f = acc[i][j][r] + bc;
          if (epi == 4) {
            if (c < 256) outf[(size_t)m * 256 + c] = f;
            else if (c < 512) outf[(size_t)M * 256 + (size_t)m * 256 + (c - 256)] = f;
            else outb[(size_t)m * 256 + (c - 512)] = f2b(f);
          } else {
            const size_t o = (size_t)m * NC + c;
            if (epi == 0) {
              outb[o] = f2b(f);
            } else if (epi == 1) {
              outf[o] = f;
            } else if (epi == 2) {
              outf[o] = resf[o] + sc * f;  // same thread reads+writes o (in-place safe)
            } else {
              outb[o] = f2b(0.5f * f * (1.f + erff(f * 0.70710678118654752f)));
            }
          }
        }
      }
    }
  }
}

extern "C" void kernel_launch(void* const* d_in, const int* in_sizes, int n_in,
                              void* d_out, int out_size, void* d_ws, size_t ws_size,
                              hipStream_t stream) {
  (void)in_sizes; (void)n_in; (void)out_size; (void)ws_size;
  const float* x   = (const float*)d_in[0];
  const int* ei    = (const int*)d_in[1];
  const float* ef  = (const float*)d_in[2];
  const float* ew  = (const float*)d_in[3];
  const float* Wq  = (const float*)d_in[4];
  const float* bq  = (const float*)d_in[5];
  const float* Wk  = (const float*)d_in[6];
  const float* bk  = (const float*)d_in[7];
  const float* Wv  = (const float*)d_in[8];
  const float* bv  = (const float*)d_in[9];
  const float* We  = (const float*)d_in[10];
  const float* bel = (const float*)d_in[11];
  const float* Wo  = (const float*)d_in[12];
  const float* bo  = (const float*)d_in[13];
  const float* W1  = (const float*)d_in[14];
  const float* b1  = (const float*)d_in[15];
  const float* W2  = (const float*)d_in[16];
  const float* b2  = (const float*)d_in[17];
  const float* g1  = (const float*)d_in[18];
  const float* be1 = (const float*)d_in[19];
  const float* g2  = (const float*)d_in[20];
  const float* be2 = (const float*)d_in[21];
  const float* alpha = (const float*)d_in[22];
  const float* beta  = (const float*)d_in[23];

  // ---- workspace (~166 MB), small index arrays first ----
  char* w = (char*)d_ws;
  auto alloc = [&](size_t b) { char* p = w; w += (b + 255) & ~(size_t)255; return p; };

  int* counts          = (int*)alloc((size_t)(NN + 1) * 4);   // counts[NN] = global cursor
  int* offs            = (int*)alloc((size_t)NN * 4);
  int* cursor          = (int*)alloc((size_t)NN * 4);
  int* sorted          = (int*)alloc((size_t)NE * 4);
  float* mxbuf         = (float*)alloc((size_t)NN * 8 * 4);
  float* invbuf        = (float*)alloc((size_t)NN * 8 * 4);
  float* bqkv          = (float*)alloc((size_t)768 * 4);
  unsigned short* wbf  = (unsigned short*)alloc((size_t)786432 * 2);   // bf16 weights pool
  unsigned short* xn   = (unsigned short*)alloc((size_t)NN * 256 * 2); // agg aliases xn
  float* qf            = (float*)alloc((size_t)NN * 256 * 4);          // h1 = qf..kf (102.4MB bf16)
  float* kf            = (float*)alloc((size_t)NN * 256 * 4);          // contiguous after qf
  unsigned short* vb   = (unsigned short*)alloc((size_t)NN * 256 * 2); // xn2 aliases vb

  unsigned short* wq_bf = wbf;                 // [768x256] contiguous Wq|Wk|Wv block
  unsigned short* wo_bf = wbf + 196608;
  unsigned short* w1_bf = wbf + 262144;
  unsigned short* w2_bf = wbf + 524288;

  unsigned short* agg = xn;   // xn dead after QKV GEMM
  unsigned short* xn2 = vb;   // vb dead after k_attn_agg
  unsigned short* h1  = (unsigned short*)qf;  // qf+kf dead after attention: [N,1024] bf16

  float* out_x   = (float*)d_out;                         // also serves as x_mid (in-place epi-2)
  float* scores  = (float*)d_out + (size_t)NN * 256;      // [E,8] f32 -> becomes attn weights in place

  const int* src = ei;
  const int* dst = ei + NE;

  hipMemsetAsync(counts, 0, (size_t)(NN + 1) * 4, stream);
  k_count<<<dim3((NE + 255) / 256), dim3(256), 0, stream>>>(dst, counts, NE);
  k_reserve<<<dim3((NN + 255) / 256), dim3(256), 0, stream>>>(counts, offs, cursor, counts + NN, NN);
  k_scatter<<<dim3((NE + 255) / 256), dim3(256), 0, stream>>>(dst, cursor, sorted, NE);

  // all weight conversions + bias concat in one launch
  k_cvt_all<<<dim3((786432 + 768 + 255) / 256), dim3(256), 0, stream>>>(
      Wq, Wk, Wv, Wo, W1, W2, bq, bk, bv, wbf, bqkv);

  k_ln<<<dim3(NN / 4), dim3(256), 0, stream>>>(x, g1, be1, xn, NN);

  dim3 gB(256);
  dim3 gQKV((NN + 127) / 128, 6);  // NC=768 merged QKV
  dim3 gQ((NN + 127) / 128, 2);    // NC=256 tiles
  dim3 gF1((NN + 127) / 128, 8);   // NC=1024 tiles
  // merged QKV: q,k f32 (precision-critical for scores); v bf16 (feeds bf16 aggregation)
  k_gemm<<<gQKV, gB, 0, stream>>>(xn, wq_bf, bqkv, NN, 768, 256, 4, vb, qf, nullptr, nullptr);

  k_attn_score<<<dim3(NN / 4), dim3(256), 0, stream>>>(qf, kf, We, bel, src, ew, ef,
                                                       offs, counts, sorted, scores, mxbuf);
  k_attn_agg<<<dim3(NN / 4), dim3(256), 0, stream>>>(vb, src, offs, counts, sorted,
                                                     scores, mxbuf, invbuf, agg);
  k_norm<<<dim3((NE * 8 + 255) / 256), dim3(256), 0, stream>>>(dst, mxbuf, invbuf, scores);

  // x_mid (= d_out x-half) = x + alpha*(agg @ Wo^T + bo)
  k_gemm<<<gQ, gB, 0, stream>>>(agg, wo_bf, bo, NN, 256, 256, 2, nullptr, out_x, x, alpha);

  k_ln<<<dim3(NN / 4), dim3(256), 0, stream>>>(out_x, g2, be2, xn2, NN);

  // h1 = gelu(xn2 @ W1^T + b1)  (bf16, overwrites qf..kf)
  k_gemm<<<gF1, gB, 0, stream>>>(xn2, w1_bf, b1, NN, 1024, 256, 3, h1, nullptr, nullptr, nullptr);

  // out_x = x_mid + beta*(h1 @ W2^T + b2)   (in-place per-element)
  k_gemm<<<gQ, gB, 0, stream>>>(h1, w2_bf, b2, NN, 256, 1024, 2, nullptr, out_x, out_x, beta);
}

// Round 8
// 1538.282 us; speedup vs baseline: 1.0212x; 1.0037x over previous
//
#include <hip/hip_runtime.h>

typedef short s16x8 __attribute__((ext_vector_type(8)));
typedef float f32x4 __attribute__((ext_vector_type(4)));

static constexpr int NN = 50000;
static constexpr int NE = 1600000;

__device__ __forceinline__ unsigned short f2b(float f) {
  union { float f; unsigned u; } c; c.f = f;
  unsigned x = c.u;
  x += 0x7fffu + ((x >> 16) & 1u);
  return (unsigned short)(x >> 16);
}
__device__ __forceinline__ unsigned short f2h(float f) {
  union { _Float16 h; unsigned short u; } c;
  c.h = (_Float16)f;  // RNE f32->f16
  return c.u;
}
__device__ __forceinline__ float h2f(unsigned short u) {
  union { unsigned short u; _Float16 h; } c;
  c.u = u;
  return (float)c.h;
}
__device__ __forceinline__ int clampi(int v, int lo, int hi) {
  return v < lo ? lo : (v > hi ? hi : v);
}
__device__ __forceinline__ int rdl_i(int v, int l) {
  return __builtin_amdgcn_readlane(v, l);
}
__device__ __forceinline__ float rdl_f(float v, int l) {
  union { float f; int i; } c; c.f = v;
  c.i = __builtin_amdgcn_readlane(c.i, l);
  return c.f;
}
// global -> LDS direct copy, 16B per lane. LDS dest is wave-uniform base;
// HW writes base + lane*16. Global src is per-lane.
__device__ __forceinline__ void gl_lds16(const void* g, void* l) {
  __builtin_amdgcn_global_load_lds((const __attribute__((address_space(1))) void*)g,
                                   (__attribute__((address_space(3))) void*)l, 16, 0, 0);
}

// ---------------- all weight conversions f32 -> bf16 + QKV bias concat, ONE launch
__global__ __launch_bounds__(256) void k_cvt_all(
    const float* __restrict__ Wq, const float* __restrict__ Wk,
    const float* __restrict__ Wv, const float* __restrict__ Wo,
    const float* __restrict__ W1, const float* __restrict__ W2,
    const float* __restrict__ bq, const float* __restrict__ bk,
    const float* __restrict__ bv, unsigned short* __restrict__ wbf,
    float* __restrict__ bqkv) {
  const int i = blockIdx.x * 256 + threadIdx.x;
  if (i < 786432) {
    float v;
    if (i < 65536) v = Wq[i];
    else if (i < 131072) v = Wk[i - 65536];
    else if (i < 196608) v = Wv[i - 131072];
    else if (i < 262144) v = Wo[i - 196608];
    else if (i < 524288) v = W1[i - 262144];
    else v = W2[i - 524288];
    wbf[i] = f2b(v);
  } else if (i < 786432 + 768) {
    const int j = i - 786432;
    bqkv[j] = (j < 256) ? bq[j] : (j < 512 ? bk[j - 256] : bv[j - 512]);
  }
}

// ---------------- CSR build ----------------
__global__ __launch_bounds__(256) void k_count(const int* __restrict__ dst,
                                               int* __restrict__ counts, int E) {
  const int e = blockIdx.x * 256 + threadIdx.x;
  if (e < E) atomicAdd(&counts[clampi(dst[e], 0, NN - 1)], 1);
}

// wave-scan reserve: one atomic per wave instead of 50000 same-address atomics.
__global__ __launch_bounds__(256) void k_reserve(const int* __restrict__ counts,
                                                 int* __restrict__ offs,
                                                 int* __restrict__ cursor,
                                                 int* __restrict__ counter, int n) {
  const int i = blockIdx.x * 256 + threadIdx.x;
  const int lane = threadIdx.x & 63;
  const int c = (i < n) ? counts[i] : 0;
  int pre = c;
#pragma unroll
  for (int m = 1; m < 64; m <<= 1) {
    const int t = __shfl_up(pre, m);
    if (lane >= m) pre += t;
  }
  const int wavesum = __shfl(pre, 63);
  int base = 0;
  if (lane == 0) base = atomicAdd(counter, wavesum);
  base = __shfl(base, 0);
  const int pos = base + pre - c;  // exclusive scan position
  if (i < n) {
    offs[i] = pos;
    cursor[i] = pos;
  }
}

__global__ __launch_bounds__(256) void k_scatter(const int* __restrict__ dst,
                                                 int* __restrict__ cursor,
                                                 int* __restrict__ sorted, int E) {
  const int e = blockIdx.x * 256 + threadIdx.x;
  if (e < E) {
    const int p = atomicAdd(&cursor[clampi(dst[e], 0, NN - 1)], 1);
    if (p >= 0 && p < E) sorted[p] = e;
  }
}

// ---------------- LayerNorm: f32 in -> bf16 out (one wave per row of 256) ----------------
__global__ __launch_bounds__(256) void k_ln(const float* __restrict__ x,
                                            const float* __restrict__ g,
                                            const float* __restrict__ b,
                                            unsigned short* __restrict__ out, int n) {
  const int row = blockIdx.x * 4 + (threadIdx.x >> 6);
  if (row >= n) return;
  const int lane = threadIdx.x & 63;
  float4 xv = *(const float4*)(x + (size_t)row * 256 + 4 * lane);
  float v0 = xv.x, v1 = xv.y, v2 = xv.z, v3 = xv.w;
  float s = v0 + v1 + v2 + v3;
  float ss = v0 * v0 + v1 * v1 + v2 * v2 + v3 * v3;
#pragma unroll
  for (int m = 1; m < 64; m <<= 1) {
    s += __shfl_xor(s, m);
    ss += __shfl_xor(ss, m);
  }
  const float mu = s * (1.f / 256.f);
  const float var = ss * (1.f / 256.f) - mu * mu;
  const float rs = rsqrtf(var + 1e-5f);
  float4 gv = *(const float4*)(g + 4 * lane);
  float4 bv = *(const float4*)(b + 4 * lane);
  ushort4 o;
  o.x = f2b((v0 - mu) * rs * gv.x + bv.x);
  o.y = f2b((v1 - mu) * rs * gv.y + bv.y);
  o.z = f2b((v2 - mu) * rs * gv.z + bv.z);
  o.w = f2b((v3 - mu) * rs * gv.w + bv.w);
  *(ushort4*)(out + (size_t)row * 256 + 4 * lane) = o;
}

// ---------------- attention A: per-edge scores + per-(node,head) max (depth-2 pipeline)
// k stored as f16 (512B/row vs 1KB f32): halves the dominant k-row gather traffic.
__global__ __launch_bounds__(256) void k_attn_score(
    const float* __restrict__ q, const unsigned short* __restrict__ k,
    const float* __restrict__ We, const float* __restrict__ be,
    const int* __restrict__ src, const float* __restrict__ ew,
    const float* __restrict__ ef, const int* __restrict__ offs,
    const int* __restrict__ counts, const int* __restrict__ sorted,
    float* __restrict__ scores, float* __restrict__ mxbuf) {
  __shared__ float WeS[32][36];
  __shared__ float beS[32];
  const int t = threadIdx.x;
  for (int i = t; i < 1024; i += 256) WeS[i >> 5][i & 31] = We[i];
  if (t < 32) beS[t] = be[t];
  __syncthreads();
  const int node = blockIdx.x * 4 + (t >> 6);
  if (node >= NN) return;
  const int lane = t & 63;
  const int h = lane >> 3;
  const int s8 = lane & 7;
  const int d0 = 4 * s8;
  const float scale = 0.17677669529663689f;  // 1/sqrt(32)

  float4 qv = *(const float4*)(q + (size_t)node * 256 + 4 * lane);
  const float qarr[4] = {qv.x, qv.y, qv.z, qv.w};

  float w0 = 0.f, w1 = 0.f, w2 = 0.f, w3 = 0.f, qb = 0.f;
#pragma unroll
  for (int t8 = 0; t8 < 8; ++t8) {
#pragma unroll
    for (int u = 0; u < 4; ++u) {
      const float qj = __shfl(qarr[u], 8 * h + t8);
      const int j = 4 * t8 + u;
      w0 += qj * WeS[j][d0 + 0];
      w1 += qj * WeS[j][d0 + 1];
      w2 += qj * WeS[j][d0 + 2];
      w3 += qj * WeS[j][d0 + 3];
      qb += qj * beS[j];
    }
  }

  const int beg = clampi(offs[node], 0, NE);
  const int cnt = clampi(counts[node], 0, NE - beg);

  float mx = -3.0e38f;
  for (int c = 0; c < cnt; c += 64) {
    const int ccnt = min(64, cnt - c);
    int eid_l = 0, s_l = 0;
    float ew_l = 0.f;
    if (lane < ccnt) {
      eid_l = clampi(sorted[beg + c + lane], 0, NE - 1);
      s_l = clampi(src[eid_l], 0, NN - 1);
      ew_l = ew[eid_l];
    }
    ushort4 kb0 = {0, 0, 0, 0}, kb1 = {0, 0, 0, 0};
    float4 eb0 = {0, 0, 0, 0}, eb1 = {0, 0, 0, 0};
    {
      const int s0 = rdl_i(s_l, 0), e0 = rdl_i(eid_l, 0);
      kb0 = *(const ushort4*)(k + (size_t)s0 * 256 + 4 * lane);
      eb0 = *(const float4*)(ef + (size_t)e0 * 32 + d0);
    }
    if (ccnt > 1) {
      const int s1 = rdl_i(s_l, 1), e1 = rdl_i(eid_l, 1);
      kb1 = *(const ushort4*)(k + (size_t)s1 * 256 + 4 * lane);
      eb1 = *(const float4*)(ef + (size_t)e1 * 32 + d0);
    }
    for (int j = 0; j < ccnt; ++j) {
      ushort4 kn = kb1;
      float4 en = eb1;
      if (j + 2 < ccnt) {
        const int sn = rdl_i(s_l, j + 2), enid = rdl_i(eid_l, j + 2);
        kn = *(const ushort4*)(k + (size_t)sn * 256 + 4 * lane);
        en = *(const float4*)(ef + (size_t)enid * 32 + d0);
      }
      const float wgt = rdl_f(ew_l, j);
      const int eid = rdl_i(eid_l, j);
      float p = qv.x * h2f(kb0.x) + qv.y * h2f(kb0.y) + qv.z * h2f(kb0.z) + qv.w * h2f(kb0.w) +
                w0 * eb0.x + w1 * eb0.y + w2 * eb0.z + w3 * eb0.w;
      p += __shfl_xor(p, 1);
      p += __shfl_xor(p, 2);
      p += __shfl_xor(p, 4);
      const float scr = (p + qb) * scale * wgt;
      mx = fmaxf(mx, scr);
      if (s8 == 0) scores[(size_t)eid * 8 + h] = scr;
      kb0 = kb1; eb0 = eb1; kb1 = kn; eb1 = en;
    }
  }
  if (s8 == 0) mxbuf[(size_t)node * 8 + h] = mx;
}

// ---------------- attention B: exp/sum + V aggregation; stores inv for k_norm
__global__ __launch_bounds__(256) void k_attn_agg(
    const unsigned short* __restrict__ v, const int* __restrict__ src,
    const int* __restrict__ offs, const int* __restrict__ counts,
    const int* __restrict__ sorted, const float* __restrict__ scores,
    const float* __restrict__ mxbuf, float* __restrict__ invbuf,
    unsigned short* __restrict__ agg) {
  const int node = blockIdx.x * 4 + (threadIdx.x >> 6);
  if (node >= NN) return;
  const int lane = threadIdx.x & 63;
  const int h = lane >> 3;
  const int s8 = lane & 7;

  const int beg = clampi(offs[node], 0, NE);
  const int cnt = clampi(counts[node], 0, NE - beg);
  const float mx = mxbuf[(size_t)node * 8 + h];

  float a0 = 0.f, a1 = 0.f, a2 = 0.f, a3 = 0.f, ssum = 0.f;
  for (int c = 0; c < cnt; c += 64) {
    const int ccnt = min(64, cnt - c);
    int eid_l = 0, s_l = 0;
    if (lane < ccnt) {
      eid_l = clampi(sorted[beg + c + lane], 0, NE - 1);
      s_l = clampi(src[eid_l], 0, NN - 1);
    }
    ushort4 vb0 = {0, 0, 0, 0}, vb1 = {0, 0, 0, 0};
    float sc0 = 0.f, sc1 = 0.f;
    {
      const int s0 = rdl_i(s_l, 0), e0 = rdl_i(eid_l, 0);
      vb0 = *(const ushort4*)(v + (size_t)s0 * 256 + 4 * lane);
      sc0 = scores[(size_t)e0 * 8 + h];
    }
    if (ccnt > 1) {
      const int s1 = rdl_i(s_l, 1), e1 = rdl_i(eid_l, 1);
      vb1 = *(const ushort4*)(v + (size_t)s1 * 256 + 4 * lane);
      sc1 = scores[(size_t)e1 * 8 + h];
    }
    for (int j = 0; j < ccnt; ++j) {
      ushort4 vn = vb1;
      float scn = sc1;
      if (j + 2 < ccnt) {
        const int sn = rdl_i(s_l, j + 2), enid = rdl_i(eid_l, j + 2);
        vn = *(const ushort4*)(v + (size_t)sn * 256 + 4 * lane);
        scn = scores[(size_t)enid * 8 + h];
      }
      const float e = __expf(sc0 - mx);
      ssum += e;
      union { unsigned u; float f; } c0, c1, c2, c3;
      c0.u = ((unsigned)vb0.x) << 16; c1.u = ((unsigned)vb0.y) << 16;
      c2.u = ((unsigned)vb0.z) << 16; c3.u = ((unsigned)vb0.w) << 16;
      a0 += e * c0.f; a1 += e * c1.f; a2 += e * c2.f; a3 += e * c3.f;
      vb0 = vb1; sc0 = sc1; vb1 = vn; sc1 = scn;
    }
  }
  const float inv = (cnt > 0) ? 1.f / ssum : 0.f;
  ushort4 o;
  o.x = f2b(a0 * inv); o.y = f2b(a1 * inv); o.z = f2b(a2 * inv); o.w = f2b(a3 * inv);
  *(ushort4*)(agg + (size_t)node * 256 + 4 * lane) = o;
  if (s8 == 0) invbuf[(size_t)node * 8 + h] = inv;  // inv is uniform across the 8-lane group
}

// ---------------- flat per-(edge,head) weight normalization, in place.
__global__ __launch_bounds__(256) void k_norm(const int* __restrict__ dst,
                                              const float* __restrict__ mxbuf,
                                              const float* __restrict__ invbuf,
                                              float* __restrict__ scores) {
  const int idx = blockIdx.x * 256 + threadIdx.x;  // (e,h): e = idx>>3, h = idx&7
  if (idx >= NE * 8) return;
  const int e = idx >> 3;
  const int h = idx & 7;
  const int node = clampi(dst[e], 0, NN - 1);
  const float mx = mxbuf[(size_t)node * 8 + h];
  const float inv = invbuf[(size_t)node * 8 + h];
  scores[idx] = __expf(scores[idx] - mx) * inv;  // same thread reads+writes idx
}

// ---------------- NT GEMM, LDS-staged with T2 XOR-swizzle (bf16 MFMA, f32 epilogue)
// epi 0: bf16 store | 1: f32 store | 2: f32 outf[o]=resf[o]+sc*f | 3: bf16 gelu
// epi 4: merged QKV: c<256 -> outf(q) f32, c<512 -> outh(k) f16, else outb(v) bf16
__global__ __launch_bounds__(256) void k_gemm(
    const unsigned short* __restrict__ A, const unsigned short* __restrict__ W,
    const float* __restrict__ bias, int M, int NC, int K, int epi,
    unsigned short* __restrict__ outb, float* __restrict__ outf,
    unsigned short* __restrict__ outh,
    const float* __restrict__ resf, const float* __restrict__ scal) {
  __shared__ unsigned short As[128 * 64];
  __shared__ unsigned short Bs[128 * 64];
  const int t = threadIdx.x;
  const int lane = t & 63;
  const int wv = t >> 6;
  const int wr = wv >> 1;        // wave row (0..1) -> 64 M-rows
  const int wc = wv & 1;         // wave col (0..1) -> 64 NC-cols
  const int m0 = blockIdx.x * 128;
  const int c0 = blockIdx.y * 128;
  const int r16 = lane & 15;
  const int quad = lane >> 4;

  f32x4 acc[4][4];
#pragma unroll
  for (int i = 0; i < 4; ++i)
#pragma unroll
    for (int j = 0; j < 4; ++j) acc[i][j] = {0.f, 0.f, 0.f, 0.f};

  for (int k0 = 0; k0 < K; k0 += 64) {
#pragma unroll
    for (int i = 0; i < 4; ++i) {
      const int ob = wv * 1024 + i * 4096;       // wave-uniform LDS base (bytes)
      const int o = ob + lane * 16;              // this lane's linear LDS slot (bytes)
      const int row = o >> 7;
      const int colb = (o & 127) ^ ((row & 7) << 4);  // inverse-swizzled source col
      const int ra = (m0 + row < M) ? (m0 + row) : (M - 1);  // tail clamp (stores guarded)
      gl_lds16((const char*)A + ((size_t)ra * K + k0) * 2 + colb, (char*)As + ob);
      gl_lds16((const char*)W + ((size_t)(c0 + row) * K + k0) * 2 + colb, (char*)Bs + ob);
    }
    __syncthreads();
#pragma unroll
    for (int kk = 0; kk < 64; kk += 32) {
      s16x8 a[4], b[4];
#pragma unroll
      for (int i = 0; i < 4; ++i) {
        const int row = wr * 64 + 16 * i + r16;
        const int cb = (kk + quad * 8) * 2;
        a[i] = *(const s16x8*)((const char*)As + row * 128 + (cb ^ ((row & 7) << 4)));
      }
#pragma unroll
      for (int j = 0; j < 4; ++j) {
        const int row = wc * 64 + 16 * j + r16;
        const int cb = (kk + quad * 8) * 2;
        b[j] = *(const s16x8*)((const char*)Bs + row * 128 + (cb ^ ((row & 7) << 4)));
      }
#pragma unroll
      for (int i = 0; i < 4; ++i)
#pragma unroll
        for (int j = 0; j < 4; ++j)
          acc[i][j] = __builtin_amdgcn_mfma_f32_16x16x32_bf16(a[i], b[j], acc[i][j], 0, 0, 0);
    }
    __syncthreads();
  }

  const float sc = scal ? scal[0] : 0.f;
#pragma unroll
  for (int j = 0; j < 4; ++j) {
    const int c = c0 + wc * 64 + 16 * j + r16;
    const float bc = bias[c];
#pragma unroll
    for (int i = 0; i < 4; ++i) {
#pragma unroll
      for (int r = 0; r < 4; ++r) {
        const int m = m0 + wr * 64 + 16 * i + quad * 4 + r;
        if (m < M) {
          float f = acc[i][j][r] + bc;
          if (epi == 4) {
            if (c < 256) outf[(size_t)m * 256 + c] = f;
            else if (c < 512) outh[(size_t)m * 256 + (c - 256)] = f2h(f);
            else outb[(size_t)m * 256 + (c - 512)] = f2b(f);
          } else {
            const size_t o = (size_t)m * NC + c;
            if (epi == 0) {
              outb[o] = f2b(f);
            } else if (epi == 1) {
              outf[o] = f;
            } else if (epi == 2) {
              outf[o] = resf[o] + sc * f;  // same thread reads+writes o (in-place safe)
            } else {
              outb[o] = f2b(0.5f * f * (1.f + erff(f * 0.70710678118654752f)));
            }
          }
        }
      }
    }
  }
}

extern "C" void kernel_launch(void* const* d_in, const int* in_sizes, int n_in,
                              void* d_out, int out_size, void* d_ws, size_t ws_size,
                              hipStream_t stream) {
  (void)in_sizes; (void)n_in; (void)out_size; (void)ws_size;
  const float* x   = (const float*)d_in[0];
  const int* ei    = (const int*)d_in[1];
  const float* ef  = (const float*)d_in[2];
  const float* ew  = (const float*)d_in[3];
  const float* Wq  = (const float*)d_in[4];
  const float* bq  = (const float*)d_in[5];
  const float* Wk  = (const float*)d_in[6];
  const float* bk  = (const float*)d_in[7];
  const float* Wv  = (const float*)d_in[8];
  const float* bv  = (const float*)d_in[9];
  const float* We  = (const float*)d_in[10];
  const float* bel = (const float*)d_in[11];
  const float* Wo  = (const float*)d_in[12];
  const float* bo  = (const float*)d_in[13];
  const float* W1  = (const float*)d_in[14];
  const float* b1  = (const float*)d_in[15];
  const float* W2  = (const float*)d_in[16];
  const float* b2  = (const float*)d_in[17];
  const float* g1  = (const float*)d_in[18];
  const float* be1 = (const float*)d_in[19];
  const float* g2  = (const float*)d_in[20];
  const float* be2 = (const float*)d_in[21];
  const float* alpha = (const float*)d_in[22];
  const float* beta  = (const float*)d_in[23];

  // ---- workspace (~166 MB), small index arrays first ----
  char* w = (char*)d_ws;
  auto alloc = [&](size_t b) { char* p = w; w += (b + 255) & ~(size_t)255; return p; };

  int* counts          = (int*)alloc((size_t)(NN + 1) * 4);   // counts[NN] = global cursor
  int* offs            = (int*)alloc((size_t)NN * 4);
  int* cursor          = (int*)alloc((size_t)NN * 4);
  int* sorted          = (int*)alloc((size_t)NE * 4);
  float* mxbuf         = (float*)alloc((size_t)NN * 8 * 4);
  float* invbuf        = (float*)alloc((size_t)NN * 8 * 4);
  float* bqkv          = (float*)alloc((size_t)768 * 4);
  unsigned short* wbf  = (unsigned short*)alloc((size_t)786432 * 2);   // bf16 weights pool
  unsigned short* xn   = (unsigned short*)alloc((size_t)NN * 256 * 2); // agg aliases xn
  float* qf            = (float*)alloc((size_t)NN * 256 * 4);          // h1 = qf..kf (102.4MB bf16)
  float* kf            = (float*)alloc((size_t)NN * 256 * 4);          // k stored f16 (uses half)
  unsigned short* vb   = (unsigned short*)alloc((size_t)NN * 256 * 2); // xn2 aliases vb

  unsigned short* wq_bf = wbf;                 // [768x256] contiguous Wq|Wk|Wv block
  unsigned short* wo_bf = wbf + 196608;
  unsigned short* w1_bf = wbf + 262144;
  unsigned short* w2_bf = wbf + 524288;

  unsigned short* kh  = (unsigned short*)kf;  // k as f16 [N,256]
  unsigned short* agg = xn;   // xn dead after QKV GEMM
  unsigned short* xn2 = vb;   // vb dead after k_attn_agg
  unsigned short* h1  = (unsigned short*)qf;  // qf+kf dead after attention: [N,1024] bf16

  float* out_x   = (float*)d_out;                         // also serves as x_mid (in-place epi-2)
  float* scores  = (float*)d_out + (size_t)NN * 256;      // [E,8] f32 -> becomes attn weights in place

  const int* src = ei;
  const int* dst = ei + NE;

  hipMemsetAsync(counts, 0, (size_t)(NN + 1) * 4, stream);
  k_count<<<dim3((NE + 255) / 256), dim3(256), 0, stream>>>(dst, counts, NE);
  k_reserve<<<dim3((NN + 255) / 256), dim3(256), 0, stream>>>(counts, offs, cursor, counts + NN, NN);
  k_scatter<<<dim3((NE + 255) / 256), dim3(256), 0, stream>>>(dst, cursor, sorted, NE);

  // all weight conversions + bias concat in one launch
  k_cvt_all<<<dim3((786432 + 768 + 255) / 256), dim3(256), 0, stream>>>(
      Wq, Wk, Wv, Wo, W1, W2, bq, bk, bv, wbf, bqkv);

  k_ln<<<dim3(NN / 4), dim3(256), 0, stream>>>(x, g1, be1, xn, NN);

  dim3 gB(256);
  dim3 gQKV((NN + 127) / 128, 6);  // NC=768 merged QKV
  dim3 gQ((NN + 127) / 128, 2);    // NC=256 tiles
  dim3 gF1((NN + 127) / 128, 8);   // NC=1024 tiles
  // merged QKV: q f32 (read once, coalesced); k f16 (gather-BW-critical); v bf16
  k_gemm<<<gQKV, gB, 0, stream>>>(xn, wq_bf, bqkv, NN, 768, 256, 4, vb, qf, kh, nullptr, nullptr);

  k_attn_score<<<dim3(NN / 4), dim3(256), 0, stream>>>(qf, kh, We, bel, src, ew, ef,
                                                       offs, counts, sorted, scores, mxbuf);
  k_attn_agg<<<dim3(NN / 4), dim3(256), 0, stream>>>(vb, src, offs, counts, sorted,
                                                     scores, mxbuf, invbuf, agg);
  k_norm<<<dim3((NE * 8 + 255) / 256), dim3(256), 0, stream>>>(dst, mxbuf, invbuf, scores);

  // x_mid (= d_out x-half) = x + alpha*(agg @ Wo^T + bo)
  k_gemm<<<gQ, gB, 0, stream>>>(agg, wo_bf, bo, NN, 256, 256, 2, nullptr, out_x, nullptr, x, alpha);

  k_ln<<<dim3(NN / 4), dim3(256), 0, stream>>>(out_x, g2, be2, xn2, NN);

  // h1 = gelu(xn2 @ W1^T + b1)  (bf16, overwrites qf..kf)
  k_gemm<<<gF1, gB, 0, stream>>>(xn2, w1_bf, b1, NN, 1024, 256, 3, h1, nullptr, nullptr, nullptr, nullptr);

  // out_x = x_mid + beta*(h1 @ W2^T + b2)   (in-place per-element)
  k_gemm<<<gQ, gB, 0, stream>>>(h1, w2_bf, b2, NN, 256, 1024, 2, nullptr, out_x, nullptr, out_x, beta);
}